// Round 1
// baseline (3894.220 us; speedup 1.0000x reference)
//
#include <hip/hip_runtime.h>
#include <math.h>

#define Sn 2048
#define Dm 2048
#define Hn 16
#define KVn 8
#define HD 128
#define FFn 6144
#define PK 614

#define BM 64
#define BN 64
#define BK 16

// ---------------------------------------------------------------------------
// Generic tiled GEMM.  MODE: 0 = NN (C=alpha*A*B [+resid]), 1 = NT (B given as
// Bt[N][K], used for Q*K^T scores), 2 = NN gate-up (C = silu(A*B) * (A*B2)).
// 3D grid: z = head; A += z*strideA, B += (z>>bshift)*strideB, C += z*strideC.
// causal: 1 = skip blocks entirely above diagonal (scores), 2 = clamp K to
// bm0+BM (ctx over causal probs). All dims assumed multiples of tile sizes.
// ---------------------------------------------------------------------------
template<typename ACC, int MODE>
__global__ __launch_bounds__(256)
void gemm_k(const float* __restrict__ A, int lda, long long strideA,
            const float* __restrict__ B, int ldb, long long strideB, int bshift,
            const float* __restrict__ B2,
            float* __restrict__ C, int ldc, long long strideC,
            const float* __restrict__ resid,
            int M, int N, int K, float alpha, int causal)
{
    const int bx = blockIdx.x, by = blockIdx.y, bz = blockIdx.z;
    const int bm0 = by * BM, bn0 = bx * BN;
    if (MODE == 1 && causal == 1 && bn0 > bm0 + BM - 1) return;   // fully masked

    A += (long long)bz * strideA;
    B += (long long)(bz >> bshift) * strideB;
    if (MODE == 2) B2 += (long long)(bz >> bshift) * strideB;
    C += (long long)bz * strideC;

    int Keff = K;
    if (causal == 2) { int kl = bm0 + BM; if (kl < Keff) Keff = kl; }

    __shared__ float As[BK][BM + 4];
    __shared__ float Bs[BK][BN + 4];
    __shared__ float B2s[BK][BN + 4];

    const int tid = threadIdx.x;
    const int tx = tid & 15, ty = tid >> 4;

    ACC acc[4][4];
    ACC acc2[4][4];
    #pragma unroll
    for (int i = 0; i < 4; i++)
        #pragma unroll
        for (int j = 0; j < 4; j++) { acc[i][j] = (ACC)0; acc2[i][j] = (ACC)0; }

    for (int k0 = 0; k0 < Keff; k0 += BK) {
        {   // stage A: 64 rows x 16 k-cols, transposed into As[k][m]
            int c = tid & 15, r0 = tid >> 4;
            #pragma unroll
            for (int i = 0; i < 4; i++) {
                int r = r0 + 16 * i;
                As[c][r] = A[(long long)(bm0 + r) * lda + (k0 + c)];
            }
        }
        if (MODE == 1) {  // B is Bt[N][K]
            int c = tid & 15, r0 = tid >> 4;
            #pragma unroll
            for (int i = 0; i < 4; i++) {
                int r = r0 + 16 * i;
                Bs[c][r] = B[(long long)(bn0 + r) * ldb + (k0 + c)];
            }
        } else {          // B is B[K][N]
            int c = tid & 63, r0 = tid >> 6;
            #pragma unroll
            for (int i = 0; i < 4; i++) {
                int r = r0 + 4 * i;
                Bs[r][c] = B[(long long)(k0 + r) * ldb + (bn0 + c)];
                if (MODE == 2) B2s[r][c] = B2[(long long)(k0 + r) * ldb + (bn0 + c)];
            }
        }
        __syncthreads();
        #pragma unroll
        for (int kk = 0; kk < BK; kk++) {
            float4 av = *(const float4*)&As[kk][ty * 4];
            float4 bv = *(const float4*)&Bs[kk][tx * 4];
            float a_[4] = {av.x, av.y, av.z, av.w};
            float b_[4] = {bv.x, bv.y, bv.z, bv.w};
            #pragma unroll
            for (int i = 0; i < 4; i++)
                #pragma unroll
                for (int j = 0; j < 4; j++)
                    acc[i][j] += (ACC)a_[i] * (ACC)b_[j];
            if (MODE == 2) {
                float4 cv = *(const float4*)&B2s[kk][tx * 4];
                float c_[4] = {cv.x, cv.y, cv.z, cv.w};
                #pragma unroll
                for (int i = 0; i < 4; i++)
                    #pragma unroll
                    for (int j = 0; j < 4; j++)
                        acc2[i][j] += (ACC)a_[i] * (ACC)c_[j];
            }
        }
        __syncthreads();
    }

    #pragma unroll
    for (int i = 0; i < 4; i++) {
        int m = bm0 + ty * 4 + i;
        #pragma unroll
        for (int j = 0; j < 4; j++) {
            int n = bn0 + tx * 4 + j;
            float val;
            if (MODE == 2) {
                float g = (float)acc[i][j], u = (float)acc2[i][j];
                val = g / (1.0f + expf(-g)) * u;          // silu(g)*u
            } else {
                val = (float)(acc[i][j] * (ACC)alpha);
                if (resid) val += resid[(long long)m * ldc + n];
            }
            C[(long long)m * ldc + n] = val;
        }
    }
}

// ---------------------------------------------------------------------------
// RMSNorm over rows of [Sn, Dm]: out = in * rsqrt(mean(in^2)+eps) * w
// ---------------------------------------------------------------------------
__global__ __launch_bounds__(256)
void rmsnorm_k(const float* __restrict__ in, const float* __restrict__ w,
               float* __restrict__ out)
{
    const int row = blockIdx.x;
    const float* x = in + (long long)row * Dm;
    float* o = out + (long long)row * Dm;
    const int tid = threadIdx.x;
    double ss = 0.0;
    #pragma unroll
    for (int rb = 0; rb < 8; rb++) {
        float t = x[tid + rb * 256];
        ss += (double)t * (double)t;
    }
    #pragma unroll
    for (int off = 32; off > 0; off >>= 1) ss += __shfl_xor(ss, off, 64);
    __shared__ double sh[4];
    int lane = tid & 63, wv = tid >> 6;
    if (lane == 0) sh[wv] = ss;
    __syncthreads();
    double tot = sh[0] + sh[1] + sh[2] + sh[3];
    double scale = 1.0 / sqrt(tot / (double)Dm + (double)1e-6f);
    #pragma unroll
    for (int rb = 0; rb < 8; rb++) {
        int j = tid + rb * 256;
        o[j] = (float)((double)x[j] * scale * (double)w[j]);
    }
}

// ---------------------------------------------------------------------------
// RoPE tables (double), replicating numpy fp32 quantization of the angle:
// inv = fp32(1/fp32(1e6^(j/64))); ang = fp32(pos * inv); then cos/sin in double.
// ---------------------------------------------------------------------------
__global__ __launch_bounds__(256)
void rope_table_k(const int* __restrict__ positions,
                  double* __restrict__ ct, double* __restrict__ st)
{
    int idx = blockIdx.x * 256 + threadIdx.x;   // s*64 + j
    if (idx >= Sn * 64) return;
    int s = idx >> 6, j = idx & 63;
    float e = (float)j * (1.0f / 64.0f);                 // exact
    float p32 = (float)pow(1.0e6, (double)e);            // correctly-rounded fp32 pow
    float invf = (float)(1.0 / (double)p32);             // correctly-rounded fp32 div
    float ang = (float)positions[s] * invf;              // fp32 mult (matches ref)
    ct[idx] = cos((double)ang);
    st[idx] = sin((double)ang);
}

// ---------------------------------------------------------------------------
// Per-head RMSNorm + RoPE, in place on buf[s][h*HD + d]. 128 threads/block.
// ---------------------------------------------------------------------------
__global__ __launch_bounds__(128)
void qknorm_rope_k(float* __restrict__ buf, int ld, int nh,
                   const float* __restrict__ w,
                   const double* __restrict__ ct, const double* __restrict__ st)
{
    const int b = blockIdx.x;
    const int h = b % nh, s = b / nh;
    float* p = buf + (long long)s * ld + h * HD;
    const int d = threadIdx.x;
    const int pd = (d < 64) ? d + 64 : d - 64;
    float a = p[d];
    float pv = p[pd];
    double ss = (double)a * (double)a;
    #pragma unroll
    for (int o = 32; o > 0; o >>= 1) ss += __shfl_xor(ss, o, 64);
    __shared__ double sh[2];
    if ((d & 63) == 0) sh[d >> 6] = ss;
    __syncthreads();                      // also drains the global loads above
    double tot = sh[0] + sh[1];
    double scale = 1.0 / sqrt(tot / (double)HD + (double)1e-6f);
    double xn = (double)a * scale * (double)w[d];
    double pn = (double)pv * scale * (double)w[pd];
    double rot = (d < 64) ? -pn : pn;
    int j = d & 63;
    double c = ct[s * 64 + j], snv = st[s * 64 + j];
    p[d] = (float)(xn * c + rot * snv);
}

// ---------------------------------------------------------------------------
// High-precision last-row q projection (fp64): qlast[n] = x[S-1,:] . Wq[:,n]
// ---------------------------------------------------------------------------
__global__ __launch_bounds__(256)
void qlast_proj_k(const float* __restrict__ x, const float* __restrict__ Wq,
                  double* __restrict__ qlast)
{
    int n = blockIdx.x * 256 + threadIdx.x;
    const float* xr = x + (long long)(Sn - 1) * Dm;
    double acc = 0.0;
    for (int kk = 0; kk < Dm; kk++)
        acc += (double)xr[kk] * (double)Wq[(long long)kk * Dm + n];
    qlast[n] = acc;
}

__global__ __launch_bounds__(128)
void qlast_nr_k(const double* __restrict__ qlast, const float* __restrict__ w,
                const double* __restrict__ ct, const double* __restrict__ st,
                double* __restrict__ qhat)
{
    const int h = blockIdx.x, d = threadIdx.x;
    const int pd = (d < 64) ? d + 64 : d - 64;
    double a = qlast[h * HD + d];
    double pv = qlast[h * HD + pd];
    double ss = a * a;
    #pragma unroll
    for (int o = 32; o > 0; o >>= 1) ss += __shfl_xor(ss, o, 64);
    __shared__ double sh[2];
    if ((d & 63) == 0) sh[d >> 6] = ss;
    __syncthreads();
    double tot = sh[0] + sh[1];
    double scale = 1.0 / sqrt(tot / (double)HD + (double)1e-6f);
    double xn = a * scale * (double)w[d];
    double pn = pv * scale * (double)w[pd];
    double rot = (d < 64) ? -pn : pn;
    int j = d & 63;
    double c = ct[(Sn - 1) * 64 + j], snv = st[(Sn - 1) * 64 + j];
    qhat[h * HD + d] = xn * c + rot * snv;
}

// ---------------------------------------------------------------------------
// Last-row attention probabilities per head, fully fp64. One block per head.
// ---------------------------------------------------------------------------
__global__ __launch_bounds__(256)
void imp_scores_k(const double* __restrict__ qhat, const float* __restrict__ khat,
                  double* __restrict__ phead)
{
    const int h = blockIdx.x, kv = h >> 1;
    __shared__ double sc[Sn];
    __shared__ double qv[HD];
    __shared__ double sh[4];
    const int tid = threadIdx.x;
    if (tid < HD) qv[tid] = qhat[h * HD + tid];
    __syncthreads();
    const double s128 = (double)sqrtf(128.0f);
    for (int j = tid; j < Sn; j += 256) {
        const float* kr = khat + (long long)j * (KVn * HD) + kv * HD;
        double acc = 0.0;
        #pragma unroll 8
        for (int dd = 0; dd < HD; dd++) acc += qv[dd] * (double)kr[dd];
        sc[j] = acc / s128;
    }
    __syncthreads();
    double m = -1.0e300;
    for (int j = tid; j < Sn; j += 256) m = fmax(m, sc[j]);
    #pragma unroll
    for (int o = 32; o > 0; o >>= 1) m = fmax(m, __shfl_xor(m, o, 64));
    if ((tid & 63) == 0) sh[tid >> 6] = m;
    __syncthreads();
    m = fmax(fmax(sh[0], sh[1]), fmax(sh[2], sh[3]));
    __syncthreads();
    double ssum = 0.0;
    for (int j = tid; j < Sn; j += 256) {
        double e = exp(sc[j] - m);
        sc[j] = e;
        ssum += e;
    }
    #pragma unroll
    for (int o = 32; o > 0; o >>= 1) ssum += __shfl_xor(ssum, o, 64);
    if ((tid & 63) == 0) sh[tid >> 6] = ssum;
    __syncthreads();
    double tot = sh[0] + sh[1] + sh[2] + sh[3];
    for (int j = tid; j < Sn; j += 256)
        phead[(long long)h * Sn + j] = sc[j] / tot;
}

// ---------------------------------------------------------------------------
// importance = mean over heads; set [S-1]=+inf; ascending bitonic sort of
// (fp32-bits<<32 | idx)  -> first PK indices (jax top_k tie semantics).
// ---------------------------------------------------------------------------
__global__ __launch_bounds__(1024)
void imp_sort_k(const double* __restrict__ phead, float* __restrict__ out_idx)
{
    __shared__ unsigned long long keys[Sn];
    const int tid = threadIdx.x;
    for (int j = tid; j < Sn; j += 1024) {
        double s = 0.0;
        #pragma unroll
        for (int h = 0; h < Hn; h++) s += phead[(long long)h * Sn + j];
        float imp = (float)(s * (1.0 / 16.0));
        if (j == Sn - 1) imp = __builtin_inff();
        unsigned u = __float_as_uint(imp);   // imp >= 0 -> bit order == value order
        keys[j] = ((unsigned long long)u << 32) | (unsigned)j;
    }
    __syncthreads();
    for (int k = 2; k <= Sn; k <<= 1) {
        for (int jj = k >> 1; jj > 0; jj >>= 1) {
            for (int i = tid; i < Sn; i += 1024) {
                int p = i ^ jj;
                if (p > i) {
                    unsigned long long a = keys[i], b = keys[p];
                    bool up = ((i & k) == 0);
                    if ((a > b) == up) { keys[i] = b; keys[p] = a; }
                }
            }
            __syncthreads();
        }
    }
    if (tid < PK)
        out_idx[tid] = (float)(unsigned)(keys[tid] & 0xffffffffULL);
}

// ---------------------------------------------------------------------------
// Causal softmax in place on attn[h][i][j] (fp32). One block per (h,i) row.
// Writes exact zeros for j > i (matches exp(-1e9) underflow in reference).
// ---------------------------------------------------------------------------
__global__ __launch_bounds__(256)
void softmax_k(float* __restrict__ attn)
{
    const long long row = blockIdx.x;           // 0 .. Hn*Sn-1
    const int i = (int)(row & (Sn - 1));
    float* p = attn + row * Sn;
    const int tid = threadIdx.x;
    float v[8];
    float mx = -1e30f;
    #pragma unroll
    for (int rb = 0; rb < 8; rb++) {
        int j = tid + rb * 256;
        if (j <= i) { v[rb] = p[j]; mx = fmaxf(mx, v[rb]); }
        else        v[rb] = 0.0f;
    }
    #pragma unroll
    for (int o = 32; o > 0; o >>= 1) mx = fmaxf(mx, __shfl_xor(mx, o, 64));
    __shared__ float shm[4], shs[4];
    int lane = tid & 63, wv = tid >> 6;
    if (lane == 0) shm[wv] = mx;
    __syncthreads();
    mx = fmaxf(fmaxf(shm[0], shm[1]), fmaxf(shm[2], shm[3]));
    float sum = 0.0f;
    #pragma unroll
    for (int rb = 0; rb < 8; rb++) {
        int j = tid + rb * 256;
        if (j <= i) { v[rb] = expf(v[rb] - mx); sum += v[rb]; }
        else        v[rb] = 0.0f;
    }
    #pragma unroll
    for (int o = 32; o > 0; o >>= 1) sum += __shfl_xor(sum, o, 64);
    if (lane == 0) shs[wv] = sum;
    __syncthreads();
    sum = shs[0] + shs[1] + shs[2] + shs[3];
    float inv = 1.0f / sum;
    #pragma unroll
    for (int rb = 0; rb < 8; rb++) {
        int j = tid + rb * 256;
        p[j] = v[rb] * inv;
    }
}

// ---------------------------------------------------------------------------
extern "C" void kernel_launch(void* const* d_in, const int* in_sizes, int n_in,
                              void* d_out, int out_size, void* d_ws, size_t ws_size,
                              hipStream_t stream)
{
    const float* hidden    = (const float*)d_in[0];
    // d_in[1] = causal_mask (unused; mask applied by index)
    const int*   positions = (const int*)d_in[2];
    const float* in_ln_w   = (const float*)d_in[3];
    const float* post_ln_w = (const float*)d_in[4];
    const float* q_norm_w  = (const float*)d_in[5];
    const float* k_norm_w  = (const float*)d_in[6];
    const float* Wq = (const float*)d_in[7];
    const float* Wk = (const float*)d_in[8];
    const float* Wv = (const float*)d_in[9];
    const float* Wo = (const float*)d_in[10];
    const float* Wg = (const float*)d_in[11];
    const float* Wu = (const float*)d_in[12];
    const float* Wd = (const float*)d_in[13];

    float* outp   = (float*)d_out;                         // [Sn*Dm]
    float* attn   = outp + (size_t)Sn * Dm;                // [Hn*Sn*Sn]
    float* idxout = attn + (size_t)Hn * Sn * Sn;           // [PK]

    float* ws = (float*)d_ws;
    size_t of = 0;
    float* x    = ws + of; of += (size_t)Sn * Dm;          // rms(hidden); later reused as ctx
    float* q    = ws + of; of += (size_t)Sn * Dm;
    float* k    = ws + of; of += (size_t)Sn * KVn * HD;
    float* v    = ws + of; of += (size_t)Sn * KVn * HD;
    float* hbuf = ws + of; of += (size_t)Sn * Dm;
    float* y    = ws + of; of += (size_t)Sn * Dm;

    // double-precision region size (in float units): qlast 2048d + qhat 2048d
    // + phead 16*2048d + cos/sin tables 2*2048*64d
    const size_t dblf = (size_t)(2048 + 2048 + Hn * Sn + 2 * Sn * 64) * 2;

    // adaptive MLP chunk width so hg fits in ws
    size_t availf = ws_size / 4;
    int W = 64;
    const int cands[12] = {6144, 3072, 2048, 1536, 1024, 768, 512, 384, 256, 192, 128, 64};
    for (int ci = 0; ci < 12; ci++) {
        int c = cands[ci];
        if (FFn % c == 0 && of + (size_t)Sn * c + dblf <= availf) { W = c; break; }
    }
    float* hg = ws + of; of += (size_t)Sn * W;
    double* qlast = (double*)(ws + of);
    double* qhat  = qlast + 2048;
    double* phead = qhat + 2048;
    double* ct    = phead + (size_t)Hn * Sn;
    double* st    = ct + (size_t)Sn * 64;
    float* ctx = x;   // reuse: x dead after QKV + qlast projections

    const float inv_s128 = 1.0f / sqrtf(128.0f);

    // 1) input RMSNorm
    rmsnorm_k<<<Sn, 256, 0, stream>>>(hidden, in_ln_w, x);
    // 2) RoPE tables
    rope_table_k<<<(Sn * 64) / 256, 256, 0, stream>>>(positions, ct, st);
    // 3) projections: Q (fp32), K (fp64 acc -> importance-grade), V (fp32)
    gemm_k<float, 0><<<dim3(Dm / BN, Sn / BM, 1), 256, 0, stream>>>(
        x, Dm, 0, Wq, Dm, 0, 0, nullptr, q, Dm, 0, nullptr, Sn, Dm, Dm, 1.0f, 0);
    gemm_k<double, 0><<<dim3((KVn * HD) / BN, Sn / BM, 1), 256, 0, stream>>>(
        x, Dm, 0, Wk, KVn * HD, 0, 0, nullptr, k, KVn * HD, 0, nullptr, Sn, KVn * HD, Dm, 1.0f, 0);
    gemm_k<float, 0><<<dim3((KVn * HD) / BN, Sn / BM, 1), 256, 0, stream>>>(
        x, Dm, 0, Wv, KVn * HD, 0, 0, nullptr, v, KVn * HD, 0, nullptr, Sn, KVn * HD, Dm, 1.0f, 0);
    // 4) hp last-row q projection (before x is reused)
    qlast_proj_k<<<Dm / 256, 256, 0, stream>>>(x, Wq, qlast);
    // 5) per-head QK norm + RoPE (in place)
    qknorm_rope_k<<<Sn * Hn, 128, 0, stream>>>(q, Dm, Hn, q_norm_w, ct, st);
    qknorm_rope_k<<<Sn * KVn, 128, 0, stream>>>(k, KVn * HD, KVn, k_norm_w, ct, st);
    qlast_nr_k<<<Hn, 128, 0, stream>>>(qlast, q_norm_w, ct, st, qhat);
    // 6) scores = q . k^T / sqrt(HD), per head (skip upper-triangle blocks)
    gemm_k<float, 1><<<dim3(Sn / BN, Sn / BM, Hn), 256, 0, stream>>>(
        q, Dm, HD, k, KVn * HD, HD, 1, nullptr,
        attn, Sn, (long long)Sn * Sn, nullptr, Sn, Sn, HD, inv_s128, 1);
    // 7) causal softmax in place
    softmax_k<<<Hn * Sn, 256, 0, stream>>>(attn);
    // 8) importance path (fp64) + top-k prune indices
    imp_scores_k<<<Hn, 256, 0, stream>>>(qhat, k, phead);
    imp_sort_k<<<1, 1024, 0, stream>>>(phead, idxout);
    // 9) ctx = P . V per head (K clamped to causal extent)
    gemm_k<float, 0><<<dim3(HD / BN, Sn / BM, Hn), 256, 0, stream>>>(
        attn, Sn, (long long)Sn * Sn, v, KVn * HD, HD, 1, nullptr,
        ctx, Dm, HD, nullptr, Sn, HD, Sn, 1.0f, 2);
    // 10) attn_out = ctx . Wo + hidden
    gemm_k<float, 0><<<dim3(Dm / BN, Sn / BM, 1), 256, 0, stream>>>(
        ctx, Dm, 0, Wo, Dm, 0, 0, nullptr, hbuf, Dm, 0, hidden, Sn, Dm, Dm, 1.0f, 0);
    // 11) post RMSNorm
    rmsnorm_k<<<Sn, 256, 0, stream>>>(hbuf, post_ln_w, y);
    // 12) SwiGLU MLP (chunked over FF), out = hbuf + hg . Wd
    const int nch = FFn / W;
    for (int ch = 0; ch < nch; ch++) {
        gemm_k<float, 2><<<dim3(W / BN, Sn / BM, 1), 256, 0, stream>>>(
            y, Dm, 0, Wg + (size_t)ch * W, FFn, 0, 0, Wu + (size_t)ch * W,
            hg, W, 0, nullptr, Sn, W, Dm, 1.0f, 0);
        const float* rs = (ch == 0) ? hbuf : outp;
        gemm_k<float, 0><<<dim3(Dm / BN, Sn / BM, 1), 256, 0, stream>>>(
            hg, W, 0, Wd + (size_t)ch * W * Dm, Dm, 0, 0, nullptr,
            outp, Dm, 0, rs, Sn, Dm, W, 1.0f, 0);
    }
    (void)in_sizes; (void)n_in; (void)out_size;
}

// Round 2
// 2004.084 us; speedup vs baseline: 1.9431x; 1.9431x over previous
//
#include <hip/hip_runtime.h>
#include <math.h>

#define Sn 2048
#define Dm 2048
#define Hn 16
#define KVn 8
#define HD 128
#define FFn 6144
#define PK 614

#define BM 64
#define BN 64
#define BK 16

typedef __attribute__((ext_vector_type(8))) short short8;
typedef __attribute__((ext_vector_type(4))) float f32x4;

__device__ __forceinline__ short f2bf(float f) {   // RNE fp32->bf16
    unsigned u = __float_as_uint(f);
    u += 0x7fff + ((u >> 16) & 1);
    return (short)(u >> 16);
}

__device__ __forceinline__ void gload16(const void* g, void* l) {
    __builtin_amdgcn_global_load_lds((const __attribute__((address_space(1))) void*)g,
                                     (__attribute__((address_space(3))) void*)l, 16, 0, 0);
}

// ---------------------------------------------------------------------------
// fp32 vector GEMM (round-1). MODE: 0 = NN (C=alpha*A*B [+resid]), 1 = NT.
// ---------------------------------------------------------------------------
template<typename ACC, int MODE>
__global__ __launch_bounds__(256)
void gemm_k(const float* __restrict__ A, int lda, long long strideA,
            const float* __restrict__ B, int ldb, long long strideB, int bshift,
            float* __restrict__ C, int ldc, long long strideC,
            const float* __restrict__ resid,
            int M, int N, int K, float alpha, int causal)
{
    const int bx = blockIdx.x, by = blockIdx.y, bz = blockIdx.z;
    const int bm0 = by * BM, bn0 = bx * BN;
    if (MODE == 1 && causal == 1 && bn0 > bm0 + BM - 1) return;

    A += (long long)bz * strideA;
    B += (long long)(bz >> bshift) * strideB;
    C += (long long)bz * strideC;

    __shared__ float As[BK][BM + 4];
    __shared__ float Bs[BK][BN + 4];

    const int tid = threadIdx.x;
    const int tx = tid & 15, ty = tid >> 4;

    ACC acc[4][4];
    #pragma unroll
    for (int i = 0; i < 4; i++)
        #pragma unroll
        for (int j = 0; j < 4; j++) acc[i][j] = (ACC)0;

    for (int k0 = 0; k0 < K; k0 += BK) {
        {
            int c = tid & 15, r0 = tid >> 4;
            #pragma unroll
            for (int i = 0; i < 4; i++) {
                int r = r0 + 16 * i;
                As[c][r] = A[(long long)(bm0 + r) * lda + (k0 + c)];
            }
        }
        if (MODE == 1) {
            int c = tid & 15, r0 = tid >> 4;
            #pragma unroll
            for (int i = 0; i < 4; i++) {
                int r = r0 + 16 * i;
                Bs[c][r] = B[(long long)(bn0 + r) * ldb + (k0 + c)];
            }
        } else {
            int c = tid & 63, r0 = tid >> 6;
            #pragma unroll
            for (int i = 0; i < 4; i++) {
                int r = r0 + 4 * i;
                Bs[r][c] = B[(long long)(k0 + r) * ldb + (bn0 + c)];
            }
        }
        __syncthreads();
        #pragma unroll
        for (int kk = 0; kk < BK; kk++) {
            float4 av = *(const float4*)&As[kk][ty * 4];
            float4 bv = *(const float4*)&Bs[kk][tx * 4];
            float a_[4] = {av.x, av.y, av.z, av.w};
            float b_[4] = {bv.x, bv.y, bv.z, bv.w};
            #pragma unroll
            for (int i = 0; i < 4; i++)
                #pragma unroll
                for (int j = 0; j < 4; j++)
                    acc[i][j] += (ACC)a_[i] * (ACC)b_[j];
        }
        __syncthreads();
    }

    #pragma unroll
    for (int i = 0; i < 4; i++) {
        int m = bm0 + ty * 4 + i;
        #pragma unroll
        for (int j = 0; j < 4; j++) {
            int n = bn0 + tx * 4 + j;
            float val = (float)(acc[i][j] * (ACC)alpha);
            if (resid) val += resid[(long long)m * ldc + n];
            C[(long long)m * ldc + n] = val;
        }
    }
}

// ---------------------------------------------------------------------------
// bf16 MFMA GEMM, m97 structure. 128x128 tile, BK=64, global_load_lds(16B).
// A[m][k] bf16 row-major, B as Bt[n][k] bf16 row-major.
// MODE 0: fp32 C (+resid). MODE 1: dual-B, C = bf16(silu(A*B) * (A*B2)).
// MODE 2: bf16 C transposed (C[n*ldc + m]) — used for Vt.
// ---------------------------------------------------------------------------
template<int MODE>
__global__ __launch_bounds__(256)
void mgemm_k(const short* __restrict__ A, int lda,
             const short* __restrict__ B, int ldb,
             const short* __restrict__ B2,
             float* __restrict__ Cf, short* __restrict__ Cb, int ldc,
             const float* __restrict__ resid, int K)
{
    __shared__ short As[128 * 64];
    __shared__ short Bs[128 * 64];
    __shared__ short B2s[(MODE == 1) ? 128 * 64 : 16];

    const int tid = threadIdx.x, lane = tid & 63, wv = tid >> 6;
    const int wm = wv & 1, wn = wv >> 1;
    const int l15 = lane & 15, q4 = lane >> 4;
    const int bm0 = blockIdx.y * 128, bn0 = blockIdx.x * 128;

    f32x4 acc[4][4];
    f32x4 acc2[(MODE == 1) ? 4 : 1][(MODE == 1) ? 4 : 1];
    #pragma unroll
    for (int i = 0; i < 4; i++)
        #pragma unroll
        for (int j = 0; j < 4; j++) {
            acc[i][j] = (f32x4)0.0f;
            if constexpr (MODE == 1) acc2[i][j] = (f32x4)0.0f;
        }

    for (int k0 = 0; k0 < K; k0 += 64) {
        #pragma unroll
        for (int r = 0; r < 4; r++) {
            int c = (wv * 4 + r) * 64 + lane;          // 16B chunk id
            int row = c >> 3, co = (c & 7) * 8;
            gload16(A + (size_t)(bm0 + row) * lda + k0 + co, (char*)As + (size_t)c * 16);
            gload16(B + (size_t)(bn0 + row) * ldb + k0 + co, (char*)Bs + (size_t)c * 16);
            if constexpr (MODE == 1)
                gload16(B2 + (size_t)(bn0 + row) * ldb + k0 + co, (char*)B2s + (size_t)c * 16);
        }
        __syncthreads();
        #pragma unroll
        for (int kk = 0; kk < 2; kk++) {
            short8 af[4], bfr[4], b2f[4];
            #pragma unroll
            for (int i = 0; i < 4; i++)
                af[i] = *(const short8*)&As[(size_t)(wm * 64 + i * 16 + l15) * 64 + kk * 32 + q4 * 8];
            #pragma unroll
            for (int j = 0; j < 4; j++) {
                bfr[j] = *(const short8*)&Bs[(size_t)(wn * 64 + j * 16 + l15) * 64 + kk * 32 + q4 * 8];
                if constexpr (MODE == 1)
                    b2f[j] = *(const short8*)&B2s[(size_t)(wn * 64 + j * 16 + l15) * 64 + kk * 32 + q4 * 8];
            }
            #pragma unroll
            for (int i = 0; i < 4; i++)
                #pragma unroll
                for (int j = 0; j < 4; j++) {
                    acc[i][j] = __builtin_amdgcn_mfma_f32_16x16x32_bf16(af[i], bfr[j], acc[i][j], 0, 0, 0);
                    if constexpr (MODE == 1)
                        acc2[i][j] = __builtin_amdgcn_mfma_f32_16x16x32_bf16(af[i], b2f[j], acc2[i][j], 0, 0, 0);
                }
        }
        __syncthreads();
    }

    #pragma unroll
    for (int i = 0; i < 4; i++)
        #pragma unroll
        for (int j = 0; j < 4; j++)
            #pragma unroll
            for (int r = 0; r < 4; r++) {
                int m = bm0 + wm * 64 + i * 16 + q4 * 4 + r;   // C/D: col=lane&15, row=q4*4+reg
                int n = bn0 + wn * 64 + j * 16 + l15;
                float vv = acc[i][j][r];
                if constexpr (MODE == 0) {
                    if (resid) vv += resid[(size_t)m * ldc + n];
                    Cf[(size_t)m * ldc + n] = vv;
                } else if constexpr (MODE == 1) {
                    float u = acc2[i][j][r];
                    Cb[(size_t)m * ldc + n] = f2bf(vv / (1.0f + expf(-vv)) * u);
                } else {
                    Cb[(size_t)n * ldc + m] = f2bf(vv);
                }
            }
}

// ---------------------------------------------------------------------------
// ctx = P(fp32, causal) . Vt(bf16): A staged fp32 -> cvt bf16 in-register.
// grid (1, Sn/128, Hn). Output bf16 ctx[m][h*HD + n].
// ---------------------------------------------------------------------------
__global__ __launch_bounds__(256)
void ctx_k(const float* __restrict__ P, const short* __restrict__ Vt,
           short* __restrict__ Cb)
{
    __shared__ float Af[128 * 64];     // 32 KB
    __shared__ short Bs[128 * 64];     // 16 KB

    const int h = blockIdx.z;
    const float* A = P + (size_t)h * Sn * Sn;
    const short* B = Vt + (size_t)(h >> 1) * HD * Sn;

    const int tid = threadIdx.x, lane = tid & 63, wv = tid >> 6;
    const int wm = wv & 1, wn = wv >> 1;
    const int l15 = lane & 15, q4 = lane >> 4;
    const int bm0 = blockIdx.y * 128;
    const int Keff = bm0 + 128;        // causal extent

    f32x4 acc[4][4];
    #pragma unroll
    for (int i = 0; i < 4; i++)
        #pragma unroll
        for (int j = 0; j < 4; j++) acc[i][j] = (f32x4)0.0f;

    for (int k0 = 0; k0 < Keff; k0 += 64) {
        #pragma unroll
        for (int r = 0; r < 8; r++) {          // A fp32: 2048 chunks of 16B
            int c = (wv * 8 + r) * 64 + lane;
            int row = c >> 4, co = (c & 15) * 4;
            gload16(A + (size_t)(bm0 + row) * Sn + k0 + co, (char*)Af + (size_t)c * 16);
        }
        #pragma unroll
        for (int r = 0; r < 4; r++) {          // B bf16: 1024 chunks
            int c = (wv * 4 + r) * 64 + lane;
            int row = c >> 3, co = (c & 7) * 8;
            gload16(B + (size_t)row * Sn + k0 + co, (char*)Bs + (size_t)c * 16);
        }
        __syncthreads();
        #pragma unroll
        for (int kk = 0; kk < 2; kk++) {
            short8 af[4], bfr[4];
            #pragma unroll
            for (int i = 0; i < 4; i++) {
                const float* ap = &Af[(size_t)(wm * 64 + i * 16 + l15) * 64 + kk * 32 + q4 * 8];
                f32x4 a0 = *(const f32x4*)ap;
                f32x4 a1 = *(const f32x4*)(ap + 4);
                short8 t;
                t[0] = f2bf(a0[0]); t[1] = f2bf(a0[1]); t[2] = f2bf(a0[2]); t[3] = f2bf(a0[3]);
                t[4] = f2bf(a1[0]); t[5] = f2bf(a1[1]); t[6] = f2bf(a1[2]); t[7] = f2bf(a1[3]);
                af[i] = t;
            }
            #pragma unroll
            for (int j = 0; j < 4; j++)
                bfr[j] = *(const short8*)&Bs[(size_t)(wn * 64 + j * 16 + l15) * 64 + kk * 32 + q4 * 8];
            #pragma unroll
            for (int i = 0; i < 4; i++)
                #pragma unroll
                for (int j = 0; j < 4; j++)
                    acc[i][j] = __builtin_amdgcn_mfma_f32_16x16x32_bf16(af[i], bfr[j], acc[i][j], 0, 0, 0);
        }
        __syncthreads();
    }

    #pragma unroll
    for (int i = 0; i < 4; i++)
        #pragma unroll
        for (int j = 0; j < 4; j++)
            #pragma unroll
            for (int r = 0; r < 4; r++) {
                int m = bm0 + wm * 64 + i * 16 + q4 * 4 + r;
                int n = wn * 64 + j * 16 + l15;
                Cb[(size_t)m * Dm + h * HD + n] = f2bf(acc[i][j][r]);
            }
}

// ---------------------------------------------------------------------------
// Transpose-cast: Wt[c][r] (bf16) = W[row0+r][col0+c] (fp32).
// grid.x = ncols/64, grid.y = nrows/64; ldt = nrows.
// ---------------------------------------------------------------------------
__global__ __launch_bounds__(256)
void castT_k(const float* __restrict__ W, int ldw, int row0, int col0,
             short* __restrict__ Wt, int ldt)
{
    __shared__ float t[64][65];
    const int tr = threadIdx.x >> 6, tc = threadIdx.x & 63;
    const int gr = blockIdx.y * 64, gc = blockIdx.x * 64;
    #pragma unroll
    for (int rr = tr; rr < 64; rr += 4)
        t[rr][tc] = W[(size_t)(row0 + gr + rr) * ldw + col0 + gc + tc];
    __syncthreads();
    #pragma unroll
    for (int cc = tr; cc < 64; cc += 4)
        Wt[(size_t)(gc + cc) * ldt + gr + tc] = f2bf(t[tc][cc]);
}

// ---------------------------------------------------------------------------
// RMSNorm: optional fp32 out and/or bf16 out.
// ---------------------------------------------------------------------------
__global__ __launch_bounds__(256)
void rmsnorm_k(const float* __restrict__ in, const float* __restrict__ w,
               float* __restrict__ o, short* __restrict__ ob)
{
    const int row = blockIdx.x;
    const float* x = in + (long long)row * Dm;
    const int tid = threadIdx.x;
    double ss = 0.0;
    #pragma unroll
    for (int rb = 0; rb < 8; rb++) {
        float t = x[tid + rb * 256];
        ss += (double)t * (double)t;
    }
    #pragma unroll
    for (int off = 32; off > 0; off >>= 1) ss += __shfl_xor(ss, off, 64);
    __shared__ double sh[4];
    int lane = tid & 63, wvv = tid >> 6;
    if (lane == 0) sh[wvv] = ss;
    __syncthreads();
    double tot = sh[0] + sh[1] + sh[2] + sh[3];
    double scale = 1.0 / sqrt(tot / (double)Dm + (double)1e-6f);
    #pragma unroll
    for (int rb = 0; rb < 8; rb++) {
        int j = tid + rb * 256;
        float val = (float)((double)x[j] * scale * (double)w[j]);
        if (o)  o[(long long)row * Dm + j] = val;
        if (ob) ob[(long long)row * Dm + j] = f2bf(val);
    }
}

// ---------------------------------------------------------------------------
__global__ __launch_bounds__(256)
void rope_table_k(const int* __restrict__ positions,
                  double* __restrict__ ct, double* __restrict__ st)
{
    int idx = blockIdx.x * 256 + threadIdx.x;
    if (idx >= Sn * 64) return;
    int s = idx >> 6, j = idx & 63;
    float e = (float)j * (1.0f / 64.0f);
    float p32 = (float)pow(1.0e6, (double)e);
    float invf = (float)(1.0 / (double)p32);
    float ang = (float)positions[s] * invf;
    ct[idx] = cos((double)ang);
    st[idx] = sin((double)ang);
}

__global__ __launch_bounds__(128)
void qknorm_rope_k(float* __restrict__ buf, int ld, int nh,
                   const float* __restrict__ w,
                   const double* __restrict__ ct, const double* __restrict__ st)
{
    const int b = blockIdx.x;
    const int h = b % nh, s = b / nh;
    float* p = buf + (long long)s * ld + h * HD;
    const int d = threadIdx.x;
    const int pd = (d < 64) ? d + 64 : d - 64;
    float a = p[d];
    float pv = p[pd];
    double ss = (double)a * (double)a;
    #pragma unroll
    for (int o = 32; o > 0; o >>= 1) ss += __shfl_xor(ss, o, 64);
    __shared__ double sh[2];
    if ((d & 63) == 0) sh[d >> 6] = ss;
    __syncthreads();
    double tot = sh[0] + sh[1];
    double scale = 1.0 / sqrt(tot / (double)HD + (double)1e-6f);
    double xn = (double)a * scale * (double)w[d];
    double pn = (double)pv * scale * (double)w[pd];
    double rot = (d < 64) ? -pn : pn;
    int j = d & 63;
    double c = ct[s * 64 + j], snv = st[s * 64 + j];
    p[d] = (float)(xn * c + rot * snv);
}

// hp last-row q projection: block b -> n in [64b, 64b+64)
__global__ __launch_bounds__(256)
void qlast_proj_k(const float* __restrict__ x, const float* __restrict__ Wq,
                  double* __restrict__ qlast)
{
    __shared__ double part[4][64];
    const int kq = threadIdx.x >> 6, nn = threadIdx.x & 63;
    const int n = blockIdx.x * 64 + nn;
    const float* xr = x + (size_t)(Sn - 1) * Dm;
    double acc = 0.0;
    for (int k = kq; k < Dm; k += 4)
        acc += (double)xr[k] * (double)Wq[(size_t)k * Dm + n];
    part[kq][nn] = acc;
    __syncthreads();
    if (kq == 0)
        qlast[n] = part[0][nn] + part[1][nn] + part[2][nn] + part[3][nn];
}

__global__ __launch_bounds__(128)
void qlast_nr_k(const double* __restrict__ qlast, const float* __restrict__ w,
                const double* __restrict__ ct, const double* __restrict__ st,
                double* __restrict__ qhat)
{
    const int h = blockIdx.x, d = threadIdx.x;
    const int pd = (d < 64) ? d + 64 : d - 64;
    double a = qlast[h * HD + d];
    double pv = qlast[h * HD + pd];
    double ss = a * a;
    #pragma unroll
    for (int o = 32; o > 0; o >>= 1) ss += __shfl_xor(ss, o, 64);
    __shared__ double sh[2];
    if ((d & 63) == 0) sh[d >> 6] = ss;
    __syncthreads();
    double tot = sh[0] + sh[1];
    double scale = 1.0 / sqrt(tot / (double)HD + (double)1e-6f);
    double xn = a * scale * (double)w[d];
    double pn = pv * scale * (double)w[pd];
    double rot = (d < 64) ? -pn : pn;
    int j = d & 63;
    double c = ct[(Sn - 1) * 64 + j], snv = st[(Sn - 1) * 64 + j];
    qhat[h * HD + d] = xn * c + rot * snv;
}

__global__ __launch_bounds__(256)
void imp_scores_k(const double* __restrict__ qhat, const float* __restrict__ khat,
                  double* __restrict__ phead)
{
    const int h = blockIdx.x, kv = h >> 1;
    __shared__ double sc[Sn];
    __shared__ double qv[HD];
    __shared__ double sh[4];
    const int tid = threadIdx.x;
    if (tid < HD) qv[tid] = qhat[h * HD + tid];
    __syncthreads();
    const double s128 = (double)sqrtf(128.0f);
    for (int j = tid; j < Sn; j += 256) {
        const float* kr = khat + (long long)j * (KVn * HD) + kv * HD;
        double acc = 0.0;
        #pragma unroll 8
        for (int dd = 0; dd < HD; dd++) acc += qv[dd] * (double)kr[dd];
        sc[j] = acc / s128;
    }
    __syncthreads();
    double m = -1.0e300;
    for (int j = tid; j < Sn; j += 256) m = fmax(m, sc[j]);
    #pragma unroll
    for (int o = 32; o > 0; o >>= 1) m = fmax(m, __shfl_xor(m, o, 64));
    if ((tid & 63) == 0) sh[tid >> 6] = m;
    __syncthreads();
    m = fmax(fmax(sh[0], sh[1]), fmax(sh[2], sh[3]));
    __syncthreads();
    double ssum = 0.0;
    for (int j = tid; j < Sn; j += 256) {
        double e = exp(sc[j] - m);
        sc[j] = e;
        ssum += e;
    }
    #pragma unroll
    for (int o = 32; o > 0; o >>= 1) ssum += __shfl_xor(ssum, o, 64);
    if ((tid & 63) == 0) sh[tid >> 6] = ssum;
    __syncthreads();
    double tot = sh[0] + sh[1] + sh[2] + sh[3];
    for (int j = tid; j < Sn; j += 256)
        phead[(long long)h * Sn + j] = sc[j] / tot;
}

__global__ __launch_bounds__(1024)
void imp_sort_k(const double* __restrict__ phead, float* __restrict__ out_idx)
{
    __shared__ unsigned long long keys[Sn];
    const int tid = threadIdx.x;
    for (int j = tid; j < Sn; j += 1024) {
        double s = 0.0;
        #pragma unroll
        for (int h = 0; h < Hn; h++) s += phead[(long long)h * Sn + j];
        float imp = (float)(s * (1.0 / 16.0));
        if (j == Sn - 1) imp = __builtin_inff();
        unsigned u = __float_as_uint(imp);
        keys[j] = ((unsigned long long)u << 32) | (unsigned)j;
    }
    __syncthreads();
    for (int k = 2; k <= Sn; k <<= 1) {
        for (int jj = k >> 1; jj > 0; jj >>= 1) {
            for (int i = tid; i < Sn; i += 1024) {
                int p = i ^ jj;
                if (p > i) {
                    unsigned long long a = keys[i], b = keys[p];
                    bool up = ((i & k) == 0);
                    if ((a > b) == up) { keys[i] = b; keys[p] = a; }
                }
            }
            __syncthreads();
        }
    }
    if (tid < PK)
        out_idx[tid] = (float)(unsigned)(keys[tid] & 0xffffffffULL);
}

__global__ __launch_bounds__(256)
void softmax_k(float* __restrict__ attn)
{
    const long long row = blockIdx.x;
    const int i = (int)(row & (Sn - 1));
    float* p = attn + row * Sn;
    const int tid = threadIdx.x;
    float v[8];
    float mx = -1e30f;
    #pragma unroll
    for (int rb = 0; rb < 8; rb++) {
        int j = tid + rb * 256;
        if (j <= i) { v[rb] = p[j]; mx = fmaxf(mx, v[rb]); }
        else        v[rb] = 0.0f;
    }
    #pragma unroll
    for (int o = 32; o > 0; o >>= 1) mx = fmaxf(mx, __shfl_xor(mx, o, 64));
    __shared__ float shm[4], shs[4];
    int lane = tid & 63, wvv = tid >> 6;
    if (lane == 0) shm[wvv] = mx;
    __syncthreads();
    mx = fmaxf(fmaxf(shm[0], shm[1]), fmaxf(shm[2], shm[3]));
    float sum = 0.0f;
    #pragma unroll
    for (int rb = 0; rb < 8; rb++) {
        int j = tid + rb * 256;
        if (j <= i) { v[rb] = expf(v[rb] - mx); sum += v[rb]; }
        else        v[rb] = 0.0f;
    }
    #pragma unroll
    for (int o = 32; o > 0; o >>= 1) sum += __shfl_xor(sum, o, 64);
    if (lane == 0) shs[wvv] = sum;
    __syncthreads();
    sum = shs[0] + shs[1] + shs[2] + shs[3];
    float inv = 1.0f / sum;
    #pragma unroll
    for (int rb = 0; rb < 8; rb++) {
        int j = tid + rb * 256;
        p[j] = v[rb] * inv;
    }
}

// ---------------------------------------------------------------------------
extern "C" void kernel_launch(void* const* d_in, const int* in_sizes, int n_in,
                              void* d_out, int out_size, void* d_ws, size_t ws_size,
                              hipStream_t stream)
{
    const float* hidden    = (const float*)d_in[0];
    const int*   positions = (const int*)d_in[2];
    const float* in_ln_w   = (const float*)d_in[3];
    const float* post_ln_w = (const float*)d_in[4];
    const float* q_norm_w  = (const float*)d_in[5];
    const float* k_norm_w  = (const float*)d_in[6];
    const float* Wq = (const float*)d_in[7];
    const float* Wk = (const float*)d_in[8];
    const float* Wv = (const float*)d_in[9];
    const float* Wo = (const float*)d_in[10];
    const float* Wg = (const float*)d_in[11];
    const float* Wu = (const float*)d_in[12];
    const float* Wd = (const float*)d_in[13];

    float* outp   = (float*)d_out;
    float* attn   = outp + (size_t)Sn * Dm;
    float* idxout = attn + (size_t)Hn * Sn * Sn;

    // ws arena (bytes). Peak ~98.3 MB; round-1 proved ws >= 132 MB.
    char* wsb = (char*)d_ws;
    const size_t MB = 1024 * 1024;
    float* x     = (float*)(wsb + 0 * MB);    // dead after qlast_proj
    float* q     = (float*)(wsb + 16 * MB);   // dead after scores
    float* kbuf  = (float*)(wsb + 32 * MB);   // dead after imp_scores
    short* x_b   = (short*)(wsb + 40 * MB);   // dead after V proj
    short* WvT   = (short*)(wsb + 48 * MB);
    short* vt    = (short*)(wsb + 52 * MB);   // [kv*HD + d][token]
    short* WoT   = (short*)(wsb + 56 * MB);
    short* ctx_b = (short*)(wsb + 64 * MB);
    float* hbuf  = (float*)(wsb + 72 * MB);
    short* y_b   = (short*)(wsb + 88 * MB);
    double* qlast = (double*)(wsb + 96 * MB);
    double* qhat  = qlast + 2048;
    double* phead = qhat + 2048;
    double* ct    = phead + (size_t)Hn * Sn;
    double* st    = ct + (size_t)Sn * 64;
    // phase-B overlays (x/q/kbuf/x_b all dead by MLP time)
    short* WgT = (short*)(wsb + 0 * MB);      // [3072][2048]
    short* WuT = (short*)(wsb + 12 * MB);
    short* hg  = (short*)(wsb + 24 * MB);     // [2048][3072]
    short* WdT = (short*)(wsb + 36 * MB);     // [2048][3072]

    const float inv_s128 = 1.0f / sqrtf(128.0f);

    // 1) input RMSNorm -> x fp32 + x_b bf16
    rmsnorm_k<<<Sn, 256, 0, stream>>>(hidden, in_ln_w, x, x_b);
    // 2) RoPE tables
    rope_table_k<<<(Sn * 64) / 256, 256, 0, stream>>>(positions, ct, st);
    // 3) Wv transpose-cast, then Q/K fp32 GEMMs + V bf16 MFMA (transposed out)
    castT_k<<<dim3(1024 / 64, 2048 / 64), 256, 0, stream>>>(Wv, KVn * HD, 0, 0, WvT, Dm);
    gemm_k<float, 0><<<dim3(Dm / BN, Sn / BM, 1), 256, 0, stream>>>(
        x, Dm, 0, Wq, Dm, 0, 0, q, Dm, 0, nullptr, Sn, Dm, Dm, 1.0f, 0);
    gemm_k<float, 0><<<dim3((KVn * HD) / BN, Sn / BM, 1), 256, 0, stream>>>(
        x, Dm, 0, Wk, KVn * HD, 0, 0, kbuf, KVn * HD, 0, nullptr, Sn, KVn * HD, Dm, 1.0f, 0);
    mgemm_k<2><<<dim3((KVn * HD) / 128, Sn / 128), 256, 0, stream>>>(
        x_b, Dm, WvT, Dm, nullptr, nullptr, vt, Sn, nullptr, Dm);
    // 4) hp last-row q projection (x still live)
    qlast_proj_k<<<Dm / 64, 256, 0, stream>>>(x, Wq, qlast);
    // 5) per-head QK norm + RoPE
    qknorm_rope_k<<<Sn * Hn, 128, 0, stream>>>(q, Dm, Hn, q_norm_w, ct, st);
    qknorm_rope_k<<<Sn * KVn, 128, 0, stream>>>(kbuf, KVn * HD, KVn, k_norm_w, ct, st);
    qlast_nr_k<<<Hn, 128, 0, stream>>>(qlast, q_norm_w, ct, st, qhat);
    // 6) scores (fp32, causal-block-skip) -> attn
    gemm_k<float, 1><<<dim3(Sn / BN, Sn / BM, Hn), 256, 0, stream>>>(
        q, Dm, HD, kbuf, KVn * HD, HD, 1,
        attn, Sn, (long long)Sn * Sn, nullptr, Sn, Sn, HD, inv_s128, 1);
    // 7) causal softmax in place
    softmax_k<<<Hn * Sn, 256, 0, stream>>>(attn);
    // 8) importance (fp64) + exact sort
    imp_scores_k<<<Hn, 256, 0, stream>>>(qhat, kbuf, phead);
    imp_sort_k<<<1, 1024, 0, stream>>>(phead, idxout);
    // 9) ctx = P.V (MFMA, fp32 P cvt in-register) -> ctx_b bf16
    castT_k<<<dim3(2048 / 64, 2048 / 64), 256, 0, stream>>>(Wo, Dm, 0, 0, WoT, Dm);
    ctx_k<<<dim3(1, Sn / 128, Hn), 256, 0, stream>>>(attn, vt, ctx_b);
    // 10) attn_out = ctx.Wo + hidden (MFMA)
    mgemm_k<0><<<dim3(Dm / 128, Sn / 128), 256, 0, stream>>>(
        ctx_b, Dm, WoT, Dm, nullptr, hbuf, nullptr, Dm, hidden, Dm);
    // 11) post RMSNorm -> y_b bf16
    rmsnorm_k<<<Sn, 256, 0, stream>>>(hbuf, post_ln_w, nullptr, y_b);
    // 12) SwiGLU MLP (MFMA), 2 chunks of FF=3072
    for (int ch = 0; ch < 2; ch++) {
        castT_k<<<dim3(3072 / 64, 2048 / 64), 256, 0, stream>>>(Wg, FFn, 0, ch * 3072, WgT, Dm);
        castT_k<<<dim3(3072 / 64, 2048 / 64), 256, 0, stream>>>(Wu, FFn, 0, ch * 3072, WuT, Dm);
        mgemm_k<1><<<dim3(3072 / 128, Sn / 128), 256, 0, stream>>>(
            y_b, Dm, WgT, Dm, WuT, nullptr, hg, 3072, nullptr, Dm);
        castT_k<<<dim3(2048 / 64, 3072 / 64), 256, 0, stream>>>(Wd, Dm, ch * 3072, 0, WdT, 3072);
        mgemm_k<0><<<dim3(Dm / 128, Sn / 128), 256, 0, stream>>>(
            hg, 3072, WdT, 3072, nullptr, outp, nullptr, Dm,
            (ch == 0) ? hbuf : outp, 3072);
    }
    (void)in_sizes; (void)n_in; (void)out_size; (void)ws_size;
}